// Round 14
// baseline (93.878 us; speedup 1.0000x reference)
//
#include <hip/hip_runtime.h>

#define NN 50000
#define NE 600000
#define DD 128
#define SLOTS 64    // deg ~ Poisson(12); P(deg>=64) ~ 1e-31 -> safe fixed-capacity buckets
#define CSTRIDE 32  // one counter per 128B cache line
#define EPB 96      // edges per block in k_initscat: 6250*96 = 600000 exactly

typedef float f32x4 __attribute__((ext_vector_type(4)));
typedef short bf16x8 __attribute__((ext_vector_type(8)));

__device__ __forceinline__ ushort f2bf(float f) {           // RNE f32 -> bf16
    uint u = __float_as_uint(f);
    u = (u + 0x7FFFu + ((u >> 16) & 1u)) >> 16;
    return (ushort)u;
}
__device__ __forceinline__ float bfhi2f(uint u) { return __uint_as_float(u & 0xFFFF0000u); }
__device__ __forceinline__ float bflo2f(uint u) { return __uint_as_float(u << 16); }

// ---------------- fused init + scatter: every block casts AND scatters ----------------
// Thread: (1) issue edge atomic early, (2) cast x chunk (independent work hides the
// atomic round-trip), (3) dependent slot store last. cntp pre-zeroed via memsetAsync.

__global__ __launch_bounds__(256) void k_initscat(const float4* __restrict__ x4, uint2* __restrict__ xb,
                                                  const float4* __restrict__ Wl4, const float4* __restrict__ W14,
                                                  uint2* __restrict__ wbl2, uint2* __restrict__ wb12,
                                                  const int* __restrict__ ei, int* __restrict__ cntp,
                                                  ushort* __restrict__ slot) {
    int b = blockIdx.x, tid = threadIdx.x;
    int i = b * 256 + tid;                  // < NN*32 exactly (grid 6250)

    // -- edge phase A: issue the random atomic as early as possible --
    int src = 0, dst = 0, pos = 0;
    bool hasE = (tid < EPB);
    if (hasE) {
        int e = b * EPB + tid;              // coalesced edge loads
        src = ei[e];
        dst = ei[NE + e];
        pos = atomicAdd(&cntp[(size_t)dst * CSTRIDE], 1);
    }

    // -- cast phase (independent of atomic result) --
    {
        float4 v = x4[i];
        uint2 o;
        o.x = (uint)f2bf(v.x) | ((uint)f2bf(v.y) << 16);
        o.y = (uint)f2bf(v.z) | ((uint)f2bf(v.w) << 16);
        xb[i] = o;
    }
    if (i < 4096) {   // 16384 f32 per weight
        float4 v = Wl4[i];
        uint2 o;
        o.x = (uint)f2bf(v.x) | ((uint)f2bf(v.y) << 16);
        o.y = (uint)f2bf(v.z) | ((uint)f2bf(v.w) << 16);
        wbl2[i] = o;
        v = W14[i];
        o.x = (uint)f2bf(v.x) | ((uint)f2bf(v.y) << 16);
        o.y = (uint)f2bf(v.z) | ((uint)f2bf(v.w) << 16);
        wb12[i] = o;
    }

    // -- edge phase B: dependent random 2B store --
    if (hasE) slot[(size_t)dst * SLOTS + pos] = (ushort)src;
}

// ---------------- gather: 16 lanes x uint4 per node, unroll-8 (proven r8 version) ----------------

__global__ __launch_bounds__(256) void k_gather(const uint4* __restrict__ xb4,
                                                const int* __restrict__ cntp,
                                                const ushort* __restrict__ slot,
                                                uint4* __restrict__ meanb4) {
    int gt = blockIdx.x * blockDim.x + threadIdx.x;
    int wid = gt >> 4;          // node
    int lane = gt & 15;         // 8 features per lane (uint4 = 4x2 bf16)
    if (wid >= NN) return;
    uint4 s = xb4[(size_t)wid * 16 + lane];   // self loop
    float a0 = bflo2f(s.x), a1 = bfhi2f(s.x), a2 = bflo2f(s.y), a3 = bfhi2f(s.y);
    float a4 = bflo2f(s.z), a5 = bfhi2f(s.z), a6 = bflo2f(s.w), a7 = bfhi2f(s.w);
    const ushort* sl = slot + (size_t)wid * SLOTS;
    int n = cntp[(size_t)wid * CSTRIDE];
    int j = 0;
    for (; j + 7 < n; j += 8) {
        int i0 = sl[j], i1 = sl[j + 1], i2 = sl[j + 2], i3 = sl[j + 3];
        int i4 = sl[j + 4], i5 = sl[j + 5], i6 = sl[j + 6], i7 = sl[j + 7];
        uint4 v0 = xb4[(size_t)i0 * 16 + lane];
        uint4 v1 = xb4[(size_t)i1 * 16 + lane];
        uint4 v2 = xb4[(size_t)i2 * 16 + lane];
        uint4 v3 = xb4[(size_t)i3 * 16 + lane];
        uint4 v4 = xb4[(size_t)i4 * 16 + lane];
        uint4 v5 = xb4[(size_t)i5 * 16 + lane];
        uint4 v6 = xb4[(size_t)i6 * 16 + lane];
        uint4 v7 = xb4[(size_t)i7 * 16 + lane];
        a0 += (bflo2f(v0.x) + bflo2f(v1.x)) + (bflo2f(v2.x) + bflo2f(v3.x))
            + (bflo2f(v4.x) + bflo2f(v5.x)) + (bflo2f(v6.x) + bflo2f(v7.x));
        a1 += (bfhi2f(v0.x) + bfhi2f(v1.x)) + (bfhi2f(v2.x) + bfhi2f(v3.x))
            + (bfhi2f(v4.x) + bfhi2f(v5.x)) + (bfhi2f(v6.x) + bfhi2f(v7.x));
        a2 += (bflo2f(v0.y) + bflo2f(v1.y)) + (bflo2f(v2.y) + bflo2f(v3.y))
            + (bflo2f(v4.y) + bflo2f(v5.y)) + (bflo2f(v6.y) + bflo2f(v7.y));
        a3 += (bfhi2f(v0.y) + bfhi2f(v1.y)) + (bfhi2f(v2.y) + bfhi2f(v3.y))
            + (bfhi2f(v4.y) + bfhi2f(v5.y)) + (bfhi2f(v6.y) + bfhi2f(v7.y));
        a4 += (bflo2f(v0.z) + bflo2f(v1.z)) + (bflo2f(v2.z) + bflo2f(v3.z))
            + (bflo2f(v4.z) + bflo2f(v5.z)) + (bflo2f(v6.z) + bflo2f(v7.z));
        a5 += (bfhi2f(v0.z) + bfhi2f(v1.z)) + (bfhi2f(v2.z) + bfhi2f(v3.z))
            + (bfhi2f(v4.z) + bfhi2f(v5.z)) + (bfhi2f(v6.z) + bfhi2f(v7.z));
        a6 += (bflo2f(v0.w) + bflo2f(v1.w)) + (bflo2f(v2.w) + bflo2f(v3.w))
            + (bflo2f(v4.w) + bflo2f(v5.w)) + (bflo2f(v6.w) + bflo2f(v7.w));
        a7 += (bfhi2f(v0.w) + bfhi2f(v1.w)) + (bfhi2f(v2.w) + bfhi2f(v3.w))
            + (bfhi2f(v4.w) + bfhi2f(v5.w)) + (bfhi2f(v6.w) + bfhi2f(v7.w));
    }
    for (; j + 3 < n; j += 4) {
        int i0 = sl[j], i1 = sl[j + 1], i2 = sl[j + 2], i3 = sl[j + 3];
        uint4 v0 = xb4[(size_t)i0 * 16 + lane];
        uint4 v1 = xb4[(size_t)i1 * 16 + lane];
        uint4 v2 = xb4[(size_t)i2 * 16 + lane];
        uint4 v3 = xb4[(size_t)i3 * 16 + lane];
        a0 += (bflo2f(v0.x) + bflo2f(v1.x)) + (bflo2f(v2.x) + bflo2f(v3.x));
        a1 += (bfhi2f(v0.x) + bfhi2f(v1.x)) + (bfhi2f(v2.x) + bfhi2f(v3.x));
        a2 += (bflo2f(v0.y) + bflo2f(v1.y)) + (bflo2f(v2.y) + bflo2f(v3.y));
        a3 += (bfhi2f(v0.y) + bfhi2f(v1.y)) + (bfhi2f(v2.y) + bfhi2f(v3.y));
        a4 += (bflo2f(v0.z) + bflo2f(v1.z)) + (bflo2f(v2.z) + bflo2f(v3.z));
        a5 += (bfhi2f(v0.z) + bfhi2f(v1.z)) + (bfhi2f(v2.z) + bfhi2f(v3.z));
        a6 += (bflo2f(v0.w) + bflo2f(v1.w)) + (bflo2f(v2.w) + bflo2f(v3.w));
        a7 += (bfhi2f(v0.w) + bfhi2f(v1.w)) + (bfhi2f(v2.w) + bfhi2f(v3.w));
    }
    for (; j < n; ++j) {
        uint4 v = xb4[(size_t)sl[j] * 16 + lane];
        a0 += bflo2f(v.x); a1 += bfhi2f(v.x);
        a2 += bflo2f(v.y); a3 += bfhi2f(v.y);
        a4 += bflo2f(v.z); a5 += bfhi2f(v.z);
        a6 += bflo2f(v.w); a7 += bfhi2f(v.w);
    }
    float rc = 1.0f / (float)(n + 1);
    uint4 o;
    o.x = (uint)f2bf(a0 * rc) | ((uint)f2bf(a1 * rc) << 16);
    o.y = (uint)f2bf(a2 * rc) | ((uint)f2bf(a3 * rc) << 16);
    o.z = (uint)f2bf(a4 * rc) | ((uint)f2bf(a5 * rc) << 16);
    o.w = (uint)f2bf(a6 * rc) | ((uint)f2bf(a7 * rc) << 16);
    meanb4[(size_t)wid * 16 + lane] = o;
}

// ---------------- MFMA MLP tail + folded output projection ----------------
// Per block: 128 partial feature sums -> dot with W2 (threads 0-2) -> 3 atomicAdds to out.
// Block 0 also adds NN*b2. d_out pre-zeroed via memsetAsync.

__global__ __launch_bounds__(256) void k_fused(const ushort* __restrict__ meanb,
                                               const uint4* __restrict__ wbl4,
                                               const uint4* __restrict__ wb14,
                                               const float* __restrict__ bl,
                                               const float* __restrict__ b1,
                                               const float* __restrict__ W2,
                                               const float* __restrict__ b2,
                                               float* __restrict__ out) {
    __shared__ ushort sWl[128 * 128];   // 32 KB bf16
    __shared__ ushort sW1[128 * 128];   // 32 KB bf16
    __shared__ ushort sAgg[4 * 2048];   // 16 KB

    int tid = threadIdx.x;
    int wid = tid >> 6, lane = tid & 63;
    int lm = lane & 15, lq = lane >> 4;

    for (int idx = tid; idx < 2048; idx += 256) {   // 128 rows x 16 granules (16 B bf16 each)
        int r = idx >> 4, g = idx & 15;
        int dst = r * 128 + ((g ^ (r & 7)) << 3);
        *(uint4*)&sWl[dst] = wbl4[idx];
        *(uint4*)&sW1[dst] = wb14[idx];
    }
    __syncthreads();

    float blr[8], b1r[8], hacc[8];
    #pragma unroll
    for (int ct = 0; ct < 8; ++ct) {
        blr[ct] = bl[ct * 16 + lm];
        b1r[ct] = b1[ct * 16 + lm];
        hacc[ct] = 0.0f;
    }

    ushort* myAgg = &sAgg[wid * 2048];
    const int NT = NN / 16;   // 3125

    for (int wt = blockIdx.x * 4 + wid; wt < NT; wt += gridDim.x * 4) {
        int nbase = wt * 16;

        bf16x8 afr[4];
        #pragma unroll
        for (int kt = 0; kt < 4; ++kt)
            afr[kt] = *(const bf16x8*)&meanb[(size_t)(nbase + lm) * 128 + kt * 32 + lq * 8];

        #pragma unroll
        for (int ct = 0; ct < 8; ++ct) {
            f32x4 acc = {0.f, 0.f, 0.f, 0.f};
            int rB = ct * 16 + lm;
            #pragma unroll
            for (int kt = 0; kt < 4; ++kt) {
                bf16x8 bfr = *(const bf16x8*)&sWl[rB * 128 + (((kt * 4 + lq) ^ (rB & 7)) << 3)];
                acc = __builtin_amdgcn_mfma_f32_16x16x32_bf16(afr[kt], bfr, acc, 0, 0, 0);
            }
            #pragma unroll
            for (int r = 0; r < 4; ++r) {
                int n = lq * 4 + r;
                int col = ct * 16 + lm;
                myAgg[n * 128 + (((col >> 3) ^ (n & 7)) << 3) + (col & 7)] = f2bf(acc[r] + blr[ct]);
            }
        }

        bf16x8 afr2[4];
        #pragma unroll
        for (int kt = 0; kt < 4; ++kt)
            afr2[kt] = *(const bf16x8*)&myAgg[lm * 128 + (((kt * 4 + lq) ^ (lm & 7)) << 3)];

        #pragma unroll
        for (int ct = 0; ct < 8; ++ct) {
            f32x4 acc = {0.f, 0.f, 0.f, 0.f};
            int rB = ct * 16 + lm;
            #pragma unroll
            for (int kt = 0; kt < 4; ++kt) {
                bf16x8 bfr = *(const bf16x8*)&sW1[rB * 128 + (((kt * 4 + lq) ^ (rB & 7)) << 3)];
                acc = __builtin_amdgcn_mfma_f32_16x16x32_bf16(afr2[kt], bfr, acc, 0, 0, 0);
            }
            float s0 = fmaxf(acc[0] + b1r[ct], 0.f);
            float s1 = fmaxf(acc[1] + b1r[ct], 0.f);
            float s2 = fmaxf(acc[2] + b1r[ct], 0.f);
            float s3 = fmaxf(acc[3] + b1r[ct], 0.f);
            hacc[ct] += (s0 + s1) + (s2 + s3);
        }
    }

    // reduce: lanes sharing lm hold disjoint node subsets
    #pragma unroll
    for (int ct = 0; ct < 8; ++ct) {
        float v = hacc[ct];
        v += __shfl_xor(v, 16);
        v += __shfl_xor(v, 32);
        hacc[ct] = v;
    }
    __syncthreads();
    float* red = (float*)sAgg;
    if (lane < 16) {
        #pragma unroll
        for (int ct = 0; ct < 8; ++ct) red[wid * 128 + ct * 16 + lane] = hacc[ct];
    }
    __syncthreads();
    if (tid < 128) {
        float s = (red[tid] + red[128 + tid]) + (red[256 + tid] + red[384 + tid]);
        red[tid] = s;          // only thread tid touches red[tid] here
    }
    __syncthreads();
    if (tid < 3) {
        float acc = 0.0f;
        #pragma unroll 4
        for (int k = 0; k < DD; ++k) acc += red[k] * W2[tid * DD + k];
        if (blockIdx.x == 0) acc += (float)NN * b2[tid];
        atomicAdd(&out[tid], acc);
    }
}

extern "C" void kernel_launch(void* const* d_in, const int* in_sizes, int n_in,
                              void* d_out, int out_size, void* d_ws, size_t ws_size,
                              hipStream_t stream) {
    const float* x  = (const float*)d_in[0];
    const int* ei   = (const int*)d_in[1];
    const float* Wl = (const float*)d_in[2];
    const float* bl = (const float*)d_in[3];
    const float* W1 = (const float*)d_in[4];
    const float* b1 = (const float*)d_in[5];
    const float* W2 = (const float*)d_in[6];
    const float* b2 = (const float*)d_in[7];

    // ws layout (~38.5 MB): xb | meanb | cntp[NN*32] | slot(ushort) | wbl | wb1
    char* wsb     = (char*)d_ws;
    ushort* xb    = (ushort*)wsb;                              // NN*DD bf16
    ushort* meanb = xb + (size_t)NN * DD;                      // NN*DD bf16
    int* cntp     = (int*)(meanb + (size_t)NN * DD);           // NN*32 int (128B/counter)
    ushort* slot  = (ushort*)(cntp + (size_t)NN * CSTRIDE);    // NN*64 ushort
    ushort* wbl   = slot + (size_t)NN * SLOTS;                 // DD*DD bf16
    ushort* wb1   = wbl + DD * DD;                             // DD*DD bf16

    hipMemsetAsync(cntp, 0, (size_t)NN * CSTRIDE * sizeof(int), stream);   // counters
    hipMemsetAsync(d_out, 0, 3 * sizeof(float), stream);                   // output accumulator

    k_initscat<<<NN * 32 / 256, 256, 0, stream>>>((const float4*)x, (uint2*)xb,
                                                  (const float4*)Wl, (const float4*)W1,
                                                  (uint2*)wbl, (uint2*)wb1, ei, cntp, slot);
    k_gather<<<(NN * 16 + 255) / 256, 256, 0, stream>>>((const uint4*)xb, cntp, slot, (uint4*)meanb);
    k_fused<<<512, 256, 0, stream>>>(meanb, (const uint4*)wbl, (const uint4*)wb1,
                                     bl, b1, W2, b2, (float*)d_out);
}

// Round 15
// 75.607 us; speedup vs baseline: 1.2417x; 1.2417x over previous
//
#include <hip/hip_runtime.h>

#define NN 50000
#define NE 600000
#define DD 128
#define SLOTS 64     // deg ~ Poisson(12); P(deg>=64) ~ 1e-31
#define NBIN 391     // ceil(NN/128) coarse bins of 128 nodes
#define BSHIFT 7
#define BINCAP 2048  // per-bin staging cap (mean 1536, sd 39 -> 13 sigma)

typedef float f32x4 __attribute__((ext_vector_type(4)));
typedef short bf16x8 __attribute__((ext_vector_type(8)));

__device__ __forceinline__ ushort f2bf(float f) {           // RNE f32 -> bf16
    uint u = __float_as_uint(f);
    u = (u + 0x7FFFu + ((u >> 16) & 1u)) >> 16;
    return (ushort)u;
}
__device__ __forceinline__ float bfhi2f(uint u) { return __uint_as_float(u & 0xFFFF0000u); }
__device__ __forceinline__ float bflo2f(uint u) { return __uint_as_float(u << 16); }

// ---------------- init: cast x + weights to bf16; binCur[b] = b*BINCAP; hsum = 0 ----------------

__global__ void k_init(const float4* __restrict__ x4, uint2* __restrict__ xb,
                       const float4* __restrict__ Wl4, const float4* __restrict__ W14,
                       uint2* __restrict__ wbl2, uint2* __restrict__ wb12,
                       int* __restrict__ binCur, float* __restrict__ hsum) {
    int i = blockIdx.x * blockDim.x + threadIdx.x;
    if (i < NN * 32) {
        float4 v = x4[i];
        uint2 o;
        o.x = (uint)f2bf(v.x) | ((uint)f2bf(v.y) << 16);
        o.y = (uint)f2bf(v.z) | ((uint)f2bf(v.w) << 16);
        xb[i] = o;
    }
    if (i < 4096) {   // 16384 f32 per weight
        float4 v = Wl4[i];
        uint2 o;
        o.x = (uint)f2bf(v.x) | ((uint)f2bf(v.y) << 16);
        o.y = (uint)f2bf(v.z) | ((uint)f2bf(v.w) << 16);
        wbl2[i] = o;
        v = W14[i];
        o.x = (uint)f2bf(v.x) | ((uint)f2bf(v.y) << 16);
        o.y = (uint)f2bf(v.z) | ((uint)f2bf(v.w) << 16);
        wb12[i] = o;
    }
    if (i < NBIN) binCur[i] = i * BINCAP;
    if (i < DD) hsum[i] = 0.0f;
}

// ---------------- partition A: LDS histogram -> few global atomics -> staged bins ----------------

__global__ __launch_bounds__(1024) void k_partA(const int* __restrict__ ei,
                                                int* __restrict__ binCur,
                                                uint* __restrict__ staged) {
    __shared__ int hist[NBIN];
    __shared__ int cur[NBIN];
    int tid = threadIdx.x;
    if (tid < NBIN) hist[tid] = 0;
    __syncthreads();

    int e0 = blockIdx.x * 4096 + tid * 4;       // NE % 4 == 0
    int4 srcs, dsts;
    bool has = e0 < NE;
    if (has) {
        srcs = *(const int4*)&ei[e0];
        dsts = *(const int4*)&ei[NE + e0];
        atomicAdd(&hist[dsts.x >> BSHIFT], 1);
        atomicAdd(&hist[dsts.y >> BSHIFT], 1);
        atomicAdd(&hist[dsts.z >> BSHIFT], 1);
        atomicAdd(&hist[dsts.w >> BSHIFT], 1);
    }
    __syncthreads();
    if (tid < NBIN) {
        int h = hist[tid];
        cur[tid] = h ? atomicAdd(&binCur[tid], h) : 0;
    }
    __syncthreads();
    if (has) {
        int p;
        p = atomicAdd(&cur[dsts.x >> BSHIFT], 1);
        staged[p] = (uint)srcs.x | ((uint)(dsts.x & 127) << 16);
        p = atomicAdd(&cur[dsts.y >> BSHIFT], 1);
        staged[p] = (uint)srcs.y | ((uint)(dsts.y & 127) << 16);
        p = atomicAdd(&cur[dsts.z >> BSHIFT], 1);
        staged[p] = (uint)srcs.z | ((uint)(dsts.z & 127) << 16);
        p = atomicAdd(&cur[dsts.w >> BSHIFT], 1);
        staged[p] = (uint)srcs.w | ((uint)(dsts.w & 127) << 16);
    }
}

// ---------------- partition B: bin -> per-node buckets entirely in LDS, coalesced out ----------------

__global__ __launch_bounds__(256) void k_partB(const uint* __restrict__ staged,
                                               const int* __restrict__ binCur,
                                               int* __restrict__ cnt,
                                               ushort* __restrict__ slot) {
    __shared__ ushort buck[128 * SLOTS];   // 16 KB
    __shared__ int lcnt[128];
    int bin = blockIdx.x, tid = threadIdx.x;
    if (tid < 128) lcnt[tid] = 0;
    __syncthreads();

    int base = bin * BINCAP;
    int total = binCur[bin] - base;
    for (int k = tid; k < total; k += 256) {
        uint pk = staged[base + k];
        int node = pk >> 16;                        // dst & 127
        int pos = atomicAdd(&lcnt[node], 1);        // LDS atomic
        buck[node * SLOTS + pos] = (ushort)(pk & 0xFFFFu);
    }
    __syncthreads();

    int nodeBase = bin * 128;
    const uint4* bs = (const uint4*)buck;           // 1024 uint4 = 16 KB
    uint4* bd = (uint4*)(slot + (size_t)nodeBase * SLOTS);
    for (int k = tid; k < 1024; k += 256) {
        int node = k >> 3;                          // 8 uint4 per 128B row
        if (nodeBase + node < NN) bd[k] = bs[k];
    }
    if (tid < 128 && nodeBase + tid < NN) cnt[nodeBase + tid] = lcnt[tid];
}

// ---------------- gather: 16 lanes x uint4 per node, unroll-8 (proven r8 version) ----------------

__global__ __launch_bounds__(256) void k_gather(const uint4* __restrict__ xb4,
                                                const int* __restrict__ cnt,
                                                const ushort* __restrict__ slot,
                                                uint4* __restrict__ meanb4) {
    int gt = blockIdx.x * blockDim.x + threadIdx.x;
    int wid = gt >> 4;          // node
    int lane = gt & 15;         // 8 features per lane
    if (wid >= NN) return;
    uint4 s = xb4[(size_t)wid * 16 + lane];   // self loop
    float a0 = bflo2f(s.x), a1 = bfhi2f(s.x), a2 = bflo2f(s.y), a3 = bfhi2f(s.y);
    float a4 = bflo2f(s.z), a5 = bfhi2f(s.z), a6 = bflo2f(s.w), a7 = bfhi2f(s.w);
    const ushort* sl = slot + (size_t)wid * SLOTS;
    int n = cnt[wid];
    int j = 0;
    for (; j + 7 < n; j += 8) {
        int i0 = sl[j], i1 = sl[j + 1], i2 = sl[j + 2], i3 = sl[j + 3];
        int i4 = sl[j + 4], i5 = sl[j + 5], i6 = sl[j + 6], i7 = sl[j + 7];
        uint4 v0 = xb4[(size_t)i0 * 16 + lane];
        uint4 v1 = xb4[(size_t)i1 * 16 + lane];
        uint4 v2 = xb4[(size_t)i2 * 16 + lane];
        uint4 v3 = xb4[(size_t)i3 * 16 + lane];
        uint4 v4 = xb4[(size_t)i4 * 16 + lane];
        uint4 v5 = xb4[(size_t)i5 * 16 + lane];
        uint4 v6 = xb4[(size_t)i6 * 16 + lane];
        uint4 v7 = xb4[(size_t)i7 * 16 + lane];
        a0 += (bflo2f(v0.x) + bflo2f(v1.x)) + (bflo2f(v2.x) + bflo2f(v3.x))
            + (bflo2f(v4.x) + bflo2f(v5.x)) + (bflo2f(v6.x) + bflo2f(v7.x));
        a1 += (bfhi2f(v0.x) + bfhi2f(v1.x)) + (bfhi2f(v2.x) + bfhi2f(v3.x))
            + (bfhi2f(v4.x) + bfhi2f(v5.x)) + (bfhi2f(v6.x) + bfhi2f(v7.x));
        a2 += (bflo2f(v0.y) + bflo2f(v1.y)) + (bflo2f(v2.y) + bflo2f(v3.y))
            + (bflo2f(v4.y) + bflo2f(v5.y)) + (bflo2f(v6.y) + bflo2f(v7.y));
        a3 += (bfhi2f(v0.y) + bfhi2f(v1.y)) + (bfhi2f(v2.y) + bfhi2f(v3.y))
            + (bfhi2f(v4.y) + bfhi2f(v5.y)) + (bfhi2f(v6.y) + bfhi2f(v7.y));
        a4 += (bflo2f(v0.z) + bflo2f(v1.z)) + (bflo2f(v2.z) + bflo2f(v3.z))
            + (bflo2f(v4.z) + bflo2f(v5.z)) + (bflo2f(v6.z) + bflo2f(v7.z));
        a5 += (bfhi2f(v0.z) + bfhi2f(v1.z)) + (bfhi2f(v2.z) + bfhi2f(v3.z))
            + (bfhi2f(v4.z) + bfhi2f(v5.z)) + (bfhi2f(v6.z) + bfhi2f(v7.z));
        a6 += (bflo2f(v0.w) + bflo2f(v1.w)) + (bflo2f(v2.w) + bflo2f(v3.w))
            + (bflo2f(v4.w) + bflo2f(v5.w)) + (bflo2f(v6.w) + bflo2f(v7.w));
        a7 += (bfhi2f(v0.w) + bfhi2f(v1.w)) + (bfhi2f(v2.w) + bfhi2f(v3.w))
            + (bfhi2f(v4.w) + bfhi2f(v5.w)) + (bfhi2f(v6.w) + bfhi2f(v7.w));
    }
    for (; j + 3 < n; j += 4) {
        int i0 = sl[j], i1 = sl[j + 1], i2 = sl[j + 2], i3 = sl[j + 3];
        uint4 v0 = xb4[(size_t)i0 * 16 + lane];
        uint4 v1 = xb4[(size_t)i1 * 16 + lane];
        uint4 v2 = xb4[(size_t)i2 * 16 + lane];
        uint4 v3 = xb4[(size_t)i3 * 16 + lane];
        a0 += (bflo2f(v0.x) + bflo2f(v1.x)) + (bflo2f(v2.x) + bflo2f(v3.x));
        a1 += (bfhi2f(v0.x) + bfhi2f(v1.x)) + (bfhi2f(v2.x) + bfhi2f(v3.x));
        a2 += (bflo2f(v0.y) + bflo2f(v1.y)) + (bflo2f(v2.y) + bflo2f(v3.y));
        a3 += (bfhi2f(v0.y) + bfhi2f(v1.y)) + (bfhi2f(v2.y) + bfhi2f(v3.y));
        a4 += (bflo2f(v0.z) + bflo2f(v1.z)) + (bflo2f(v2.z) + bflo2f(v3.z));
        a5 += (bfhi2f(v0.z) + bfhi2f(v1.z)) + (bfhi2f(v2.z) + bfhi2f(v3.z));
        a6 += (bflo2f(v0.w) + bflo2f(v1.w)) + (bflo2f(v2.w) + bflo2f(v3.w));
        a7 += (bfhi2f(v0.w) + bfhi2f(v1.w)) + (bfhi2f(v2.w) + bfhi2f(v3.w));
    }
    for (; j < n; ++j) {
        uint4 v = xb4[(size_t)sl[j] * 16 + lane];
        a0 += bflo2f(v.x); a1 += bfhi2f(v.x);
        a2 += bflo2f(v.y); a3 += bfhi2f(v.y);
        a4 += bflo2f(v.z); a5 += bfhi2f(v.z);
        a6 += bflo2f(v.w); a7 += bfhi2f(v.w);
    }
    float rc = 1.0f / (float)(n + 1);
    uint4 o;
    o.x = (uint)f2bf(a0 * rc) | ((uint)f2bf(a1 * rc) << 16);
    o.y = (uint)f2bf(a2 * rc) | ((uint)f2bf(a3 * rc) << 16);
    o.z = (uint)f2bf(a4 * rc) | ((uint)f2bf(a5 * rc) << 16);
    o.w = (uint)f2bf(a6 * rc) | ((uint)f2bf(a7 * rc) << 16);
    meanb4[(size_t)wid * 16 + lane] = o;
}

// ---------------- MFMA MLP tail (bf16 LDS-staged weights, grid-stride tiles) ----------------

__global__ __launch_bounds__(256) void k_fused(const ushort* __restrict__ meanb,
                                               const uint4* __restrict__ wbl4,
                                               const uint4* __restrict__ wb14,
                                               const float* __restrict__ bl,
                                               const float* __restrict__ b1,
                                               float* __restrict__ hsum) {
    __shared__ ushort sWl[128 * 128];   // 32 KB bf16
    __shared__ ushort sW1[128 * 128];   // 32 KB bf16
    __shared__ ushort sAgg[4 * 2048];   // 16 KB

    int tid = threadIdx.x;
    int wid = tid >> 6, lane = tid & 63;
    int lm = lane & 15, lq = lane >> 4;

    for (int idx = tid; idx < 2048; idx += 256) {
        int r = idx >> 4, g = idx & 15;
        int dst = r * 128 + ((g ^ (r & 7)) << 3);
        *(uint4*)&sWl[dst] = wbl4[idx];
        *(uint4*)&sW1[dst] = wb14[idx];
    }
    __syncthreads();

    float blr[8], b1r[8], hacc[8];
    #pragma unroll
    for (int ct = 0; ct < 8; ++ct) {
        blr[ct] = bl[ct * 16 + lm];
        b1r[ct] = b1[ct * 16 + lm];
        hacc[ct] = 0.0f;
    }

    ushort* myAgg = &sAgg[wid * 2048];
    const int NT = NN / 16;   // 3125

    for (int wt = blockIdx.x * 4 + wid; wt < NT; wt += gridDim.x * 4) {
        int nbase = wt * 16;

        bf16x8 afr[4];
        #pragma unroll
        for (int kt = 0; kt < 4; ++kt)
            afr[kt] = *(const bf16x8*)&meanb[(size_t)(nbase + lm) * 128 + kt * 32 + lq * 8];

        #pragma unroll
        for (int ct = 0; ct < 8; ++ct) {
            f32x4 acc = {0.f, 0.f, 0.f, 0.f};
            int rB = ct * 16 + lm;
            #pragma unroll
            for (int kt = 0; kt < 4; ++kt) {
                bf16x8 bfr = *(const bf16x8*)&sWl[rB * 128 + (((kt * 4 + lq) ^ (rB & 7)) << 3)];
                acc = __builtin_amdgcn_mfma_f32_16x16x32_bf16(afr[kt], bfr, acc, 0, 0, 0);
            }
            #pragma unroll
            for (int r = 0; r < 4; ++r) {
                int n = lq * 4 + r;
                int col = ct * 16 + lm;
                myAgg[n * 128 + (((col >> 3) ^ (n & 7)) << 3) + (col & 7)] = f2bf(acc[r] + blr[ct]);
            }
        }

        bf16x8 afr2[4];
        #pragma unroll
        for (int kt = 0; kt < 4; ++kt)
            afr2[kt] = *(const bf16x8*)&myAgg[lm * 128 + (((kt * 4 + lq) ^ (lm & 7)) << 3)];

        #pragma unroll
        for (int ct = 0; ct < 8; ++ct) {
            f32x4 acc = {0.f, 0.f, 0.f, 0.f};
            int rB = ct * 16 + lm;
            #pragma unroll
            for (int kt = 0; kt < 4; ++kt) {
                bf16x8 bfr = *(const bf16x8*)&sW1[rB * 128 + (((kt * 4 + lq) ^ (rB & 7)) << 3)];
                acc = __builtin_amdgcn_mfma_f32_16x16x32_bf16(afr2[kt], bfr, acc, 0, 0, 0);
            }
            float s0 = fmaxf(acc[0] + b1r[ct], 0.f);
            float s1 = fmaxf(acc[1] + b1r[ct], 0.f);
            float s2 = fmaxf(acc[2] + b1r[ct], 0.f);
            float s3 = fmaxf(acc[3] + b1r[ct], 0.f);
            hacc[ct] += (s0 + s1) + (s2 + s3);
        }
    }

    #pragma unroll
    for (int ct = 0; ct < 8; ++ct) {
        float v = hacc[ct];
        v += __shfl_xor(v, 16);
        v += __shfl_xor(v, 32);
        hacc[ct] = v;
    }
    __syncthreads();
    float* red = (float*)sAgg;
    if (lane < 16) {
        #pragma unroll
        for (int ct = 0; ct < 8; ++ct) red[wid * 128 + ct * 16 + lane] = hacc[ct];
    }
    __syncthreads();
    if (tid < 128) {
        float s = (red[tid] + red[128 + tid]) + (red[256 + tid] + red[384 + tid]);
        atomicAdd(&hsum[tid], s);
    }
}

__global__ void k_out(const float* __restrict__ hsum, const float* __restrict__ W2,
                      const float* __restrict__ b2, float* __restrict__ out) {
    int j = threadIdx.x;
    if (j < 3) {
        float acc = 0.0f;
        for (int k = 0; k < DD; ++k) acc += hsum[k] * W2[j * DD + k];
        out[j] = acc + (float)NN * b2[j];
    }
}

extern "C" void kernel_launch(void* const* d_in, const int* in_sizes, int n_in,
                              void* d_out, int out_size, void* d_ws, size_t ws_size,
                              hipStream_t stream) {
    const float* x  = (const float*)d_in[0];
    const int* ei   = (const int*)d_in[1];
    const float* Wl = (const float*)d_in[2];
    const float* bl = (const float*)d_in[3];
    const float* W1 = (const float*)d_in[4];
    const float* b1 = (const float*)d_in[5];
    const float* W2 = (const float*)d_in[6];
    const float* b2 = (const float*)d_in[7];

    // ws layout (~35.5 MB): xb | meanb | hsum | cnt | binCur(512 pad) | staged | slot | wbl | wb1
    char* wsb     = (char*)d_ws;
    ushort* xb    = (ushort*)wsb;                              // NN*DD bf16        (12.8 MB)
    ushort* meanb = xb + (size_t)NN * DD;                      // NN*DD bf16        (12.8 MB)
    float* hsum   = (float*)(meanb + (size_t)NN * DD);         // DD f32
    int* cnt      = (int*)(hsum + DD);                         // NN int
    int* binCur   = cnt + NN;                                  // 512 ints (NBIN used, padded for 16B align)
    uint* staged  = (uint*)(binCur + 512);                     // NBIN*BINCAP uint  (3.2 MB)
    ushort* slot  = (ushort*)(staged + (size_t)NBIN * BINCAP); // NN*64 ushort      (6.4 MB)
    ushort* wbl   = slot + (size_t)NN * SLOTS;                 // DD*DD bf16
    ushort* wb1   = wbl + DD * DD;                             // DD*DD bf16

    k_init<<<NN * 32 / 256, 256, 0, stream>>>((const float4*)x, (uint2*)xb,
                                              (const float4*)Wl, (const float4*)W1,
                                              (uint2*)wbl, (uint2*)wb1, binCur, hsum);
    k_partA<<<(NE + 4095) / 4096, 1024, 0, stream>>>(ei, binCur, staged);
    k_partB<<<NBIN, 256, 0, stream>>>(staged, binCur, cnt, slot);
    k_gather<<<(NN * 16 + 255) / 256, 256, 0, stream>>>((const uint4*)xb, cnt, slot, (uint4*)meanb);
    k_fused<<<512, 256, 0, stream>>>(meanb, (const uint4*)wbl, (const uint4*)wb1, bl, b1, hsum);
    k_out<<<1, 64, 0, stream>>>(hsum, W2, b2, (float*)d_out);
}